// Round 20
// baseline (360.920 us; speedup 1.0000x reference)
//
#include <hip/hip_runtime.h>
#include <stdint.h>

typedef __attribute__((ext_vector_type(8))) short short8;
typedef __attribute__((ext_vector_type(8))) _Float16 half8;
typedef __attribute__((ext_vector_type(4))) float f32x4;

__device__ __forceinline__ unsigned short f2h(float x) {
  _Float16 h = (_Float16)x;
  return __builtin_bit_cast(unsigned short, h);
}
__device__ __forceinline__ float h2f(unsigned short u) {
  return (float)__builtin_bit_cast(_Float16, u);
}

#define GLOAD16(gsrc, ldst)                                              \
  __builtin_amdgcn_global_load_lds(                                      \
      (const __attribute__((address_space(1))) void*)(gsrc),             \
      (__attribute__((address_space(3))) void*)(ldst), 16, 0, 0)

#define VM(N) asm volatile("s_waitcnt vmcnt(" #N ")" ::: "memory")
#define BARSYNC __builtin_amdgcn_s_barrier()
#define LGKM0                                                \
  do {                                                       \
    asm volatile("s_waitcnt lgkmcnt(0)" ::: "memory");       \
    __builtin_amdgcn_sched_barrier(0);                       \
  } while (0)

// ---------- split fp32 -> (hi, lo) f16, 8 elems/thread ----------
__global__ __launch_bounds__(256) void split_pair_f16_kernel(
    const float* __restrict__ in, unsigned short* __restrict__ h,
    unsigned short* __restrict__ l) {
  size_t i = (size_t)blockIdx.x * 256 + threadIdx.x;
  float4 a = ((const float4*)in)[2 * i];
  float4 b = ((const float4*)in)[2 * i + 1];
  ushort4 h0 = make_ushort4(f2h(a.x), f2h(a.y), f2h(a.z), f2h(a.w));
  ushort4 h1 = make_ushort4(f2h(b.x), f2h(b.y), f2h(b.z), f2h(b.w));
  ((ushort4*)h)[2 * i] = h0;
  ((ushort4*)h)[2 * i + 1] = h1;
  ((ushort4*)l)[2 * i] = make_ushort4(
      f2h(a.x - h2f(h0.x)), f2h(a.y - h2f(h0.y)),
      f2h(a.z - h2f(h0.z)), f2h(a.w - h2f(h0.w)));
  ((ushort4*)l)[2 * i + 1] = make_ushort4(
      f2h(b.x - h2f(h1.x)), f2h(b.y - h2f(h1.y)),
      f2h(b.z - h2f(h1.z)), f2h(b.w - h2f(h1.w)));
}

// ---------- transpose Wq/Wk/Wv [K][N] fp32 -> f16 [N][K], z selects ----
__global__ __launch_bounds__(256) void transpose_f16x3_kernel(
    const float* __restrict__ Wq, const float* __restrict__ Wk,
    const float* __restrict__ Wv, unsigned short* __restrict__ hT) {
  __shared__ float tile[32][33];
  const float* W = blockIdx.z == 0 ? Wq : blockIdx.z == 1 ? Wk : Wv;
  unsigned short* dst = hT + (size_t)blockIdx.z * 1024 * 1024;
  int r = threadIdx.x >> 3;
  int c = (threadIdx.x & 7) * 4;
  int k0 = blockIdx.y * 32, n0 = blockIdx.x * 32;
  float4 v = *(const float4*)&W[(size_t)(k0 + r) * 1024 + n0 + c];
  tile[r][c] = v.x; tile[r][c + 1] = v.y; tile[r][c + 2] = v.z; tile[r][c + 3] = v.w;
  __syncthreads();
  size_t o = (size_t)(n0 + r) * 1024 + k0 + c;
  *(ushort4*)&dst[o] = make_ushort4(f2h(tile[c + 0][r]), f2h(tile[c + 1][r]),
                                    f2h(tile[c + 2][r]), f2h(tile[c + 3][r]));
}

// ---------- transpose V [8192][1024] f16 -> vT [1024][8192] f16 ----------
__global__ __launch_bounds__(256) void transpose_v_kernel(
    const unsigned short* __restrict__ Vs, unsigned short* __restrict__ vT) {
  __shared__ unsigned short tile[32][36];
  int r = threadIdx.x >> 3;
  int c = (threadIdx.x & 7) * 4;
  int col0 = blockIdx.x * 32;
  int row0 = blockIdx.y * 32;
  ushort4 v = *(const ushort4*)&Vs[(size_t)(row0 + r) * 1024 + col0 + c];
  tile[r][c] = v.x; tile[r][c + 1] = v.y; tile[r][c + 2] = v.z; tile[r][c + 3] = v.w;
  __syncthreads();
  ushort4 o = make_ushort4(tile[c + 0][r], tile[c + 1][r],
                           tile[c + 2][r], tile[c + 3][r]);
  *(ushort4*)&vT[(size_t)(col0 + r) * 8192 + row0 + c] = o;
}

// =====================================================================
// qkv8_kernel: fused QKV projection on the R14-verified 8-phase ledger.
// 2-term f16 NT GEMM, 128x384 tile, BK=64, dbuf 2x80KB=160KB.
// Per K-tile LDS: A-hi 16KB [0,16K) | A-lo 16KB [16K,32K) | B 48KB [32K,80K);
// subtile (rowgroup, khalf) = 1KB at (rg*2+kh)*1KB (B: 32768+(cg*2+kh)*1KB).
// Half-tiles by QUADRANT USAGE: HA0 = rg {0,1,4,5} (qr=0), HA1 = +2;
// HB0 = cg {wN*6+0..2} (qc=0), HB1 = +3. Per-wave stages: A0/A1 2 gloads,
// B0/B1 3 gloads (10/tile). Quad order (0,0),(1,0),(1,1),(0,1); B persists
// 2 phases; A0 re-read at ph3. Stage map identical to g8q; vmcnt ONLY at
// ph3/ph7 keeping last 3 half-tiles = VM(8). Prologue 18 loads + VM(8);
// tail: VM(0) at ph3. K-chunk accumulation order (kk asc, hi then lo) is
// bit-identical to R17 -> absmax must not change.
// Grid (8,64)=512 = 2 balanced rounds; staged 640MB.
// =====================================================================
#define QSTA0(T, bufb)                                                    \
  _Pragma("unroll") for (int _c = 0; _c < 2; ++_c)                        \
      GLOAD16(srcA[_c] + (size_t)(T) * 64,                                \
              smem + (bufb) * 81920 + dstA[_c]);
#define QSTA1(T, bufb)                                                    \
  _Pragma("unroll") for (int _c = 0; _c < 2; ++_c)                        \
      GLOAD16(srcA[_c] + 32768 + (size_t)(T) * 64,                        \
              smem + (bufb) * 81920 + dstA[_c] + 4096);
#define QSTB0(T, bufb)                                                    \
  _Pragma("unroll") for (int _c = 0; _c < 3; ++_c)                        \
      GLOAD16(srcB[_c] + (size_t)(T) * 64,                                \
              smem + (bufb) * 81920 + dstB[_c]);
#define QSTB1(T, bufb)                                                    \
  _Pragma("unroll") for (int _c = 0; _c < 3; ++_c)                        \
      GLOAD16(srcB[_c] + 49152 + (size_t)(T) * 64,                        \
              smem + (bufb) * 81920 + dstB[_c] + 6144);

#define QRDA(bufb, qr)                                                    \
  _Pragma("unroll") for (int _i = 0; _i < 2; ++_i)                        \
  _Pragma("unroll") for (int _kk = 0; _kk < 2; ++_kk) {                   \
    const int _rg = waveM * 4 + (qr) * 2 + _i;                            \
    ahf[_i][_kk] = *(const half8*)(smem + (bufb) * 81920 +                \
        (_rg * 2 + _kk) * 1024 + lane * 16);                              \
    alf[_i][_kk] = *(const half8*)(smem + (bufb) * 81920 + 16384 +        \
        (_rg * 2 + _kk) * 1024 + lane * 16);                              \
  }
#define QRDB(bufb, qc)                                                    \
  _Pragma("unroll") for (int _j = 0; _j < 3; ++_j)                        \
  _Pragma("unroll") for (int _kk = 0; _kk < 2; ++_kk) {                   \
    const int _cg = waveN * 6 + (qc) * 3 + _j;                            \
    bfr[_j][_kk] = *(const half8*)(smem + (bufb) * 81920 + 32768 +        \
        (_cg * 2 + _kk) * 1024 + lane * 16);                              \
  }
#define QMM(qr, qc)                                                       \
  __builtin_amdgcn_s_setprio(1);                                          \
  _Pragma("unroll") for (int _kk = 0; _kk < 2; ++_kk)                     \
  _Pragma("unroll") for (int _i = 0; _i < 2; ++_i)                        \
  _Pragma("unroll") for (int _j = 0; _j < 3; ++_j) {                      \
    f32x4 _cc = acc[(qr) * 2 + _i][(qc) * 3 + _j];                        \
    _cc = __builtin_amdgcn_mfma_f32_16x16x32_f16(ahf[_i][_kk],            \
          bfr[_j][_kk], _cc, 0, 0, 0);                                    \
    _cc = __builtin_amdgcn_mfma_f32_16x16x32_f16(alf[_i][_kk],            \
          bfr[_j][_kk], _cc, 0, 0, 0);                                    \
    acc[(qr) * 2 + _i][(qc) * 3 + _j] = _cc;                              \
  }                                                                       \
  __builtin_amdgcn_s_setprio(0);

__global__ __launch_bounds__(512, 2) void qkv8_kernel(
    const unsigned short* __restrict__ Ah, const unsigned short* __restrict__ Al,
    const unsigned short* __restrict__ WT, const float* __restrict__ bq,
    const float* __restrict__ bk, const float* __restrict__ bv,
    unsigned short* __restrict__ qh, unsigned short* __restrict__ kh,
    unsigned short* __restrict__ vS) {
  __shared__ __align__(16) char smem[2 * 80 * 1024];
  const int t = threadIdx.x, wid = t >> 6, lane = t & 63;
  const int waveM = wid >> 2, waveN = wid & 3;
  const int lr0 = lane & 15, lk0 = (lane >> 4) * 8;
  const int m0 = blockIdx.y * 128, n0 = blockIdx.x * 384;

  // HA0 staging: subtile idx = 2*wid+c -> (rgI, type, khalf)
  const unsigned short* srcA[2];
  int dstA[2];
#pragma unroll
  for (int c = 0; c < 2; ++c) {
    int idx = 2 * wid + c;
    int rgI = idx >> 2, ty = (idx >> 1) & 1, kk = idx & 1;
    int rg = (rgI & 1) + ((rgI >> 1) << 2);  // {0,1,4,5}
    const unsigned short* base = ty ? Al : Ah;
    srcA[c] = base + (size_t)(m0 + rg * 16 + lr0) * 1024 + kk * 32 + lk0;
    dstA[c] = ty * 16384 + (rg * 2 + kk) * 1024;
  }
  // HB0 staging: subtile idx = 3*wid+c -> (cgI, khalf)
  const unsigned short* srcB[3];
  int dstB[3];
#pragma unroll
  for (int c = 0; c < 3; ++c) {
    int idx = 3 * wid + c;
    int cgI = idx >> 1, kk = idx & 1;
    int cg = (cgI % 3) + (cgI / 3) * 6;  // {0,1,2,6,7,8,12,13,14,18,19,20}
    srcB[c] = WT + (size_t)(n0 + cg * 16 + lr0) * 1024 + kk * 32 + lk0;
    dstB[c] = 32768 + (cg * 2 + kk) * 1024;
  }

  const int NT = 1024 >> 6, NT2 = NT >> 1;  // 16, 8
  f32x4 acc[4][6] = {};
  half8 ahf[2][2], alf[2][2], bfr[3][2];

  // prologue: tile0 {A0,B0,A1,B1} (10) + tile1 {B0,A1,B1} (8); land tile0.
  QSTA0(0, 0) QSTB0(0, 0) QSTA1(0, 0) QSTB1(0, 0)
  QSTB0(1, 1) QSTA1(1, 1) QSTB1(1, 1)
  VM(8);
  BARSYNC;
  __builtin_amdgcn_sched_barrier(0);

#pragma unroll 1
  for (int it = 0; it < NT2; ++it) {
    const int tt = 2 * it;
    const bool s2 = (tt + 2) < NT;
    const bool s3 = (tt + 3) < NT;
    // ph0: buf0 quad(0,0); stage HA0(tt+1)->buf1
    QRDA(0, 0) QRDB(0, 0)
    QSTA0(tt + 1, 1)
    BARSYNC; LGKM0; QMM(0, 0) BARSYNC;
    // ph1: quad(1,0) [B0 in regs]; stage HB0(tt+2)->buf0
    QRDA(0, 1)
    if (s2) QSTB0(tt + 2, 0)
    BARSYNC; LGKM0; QMM(1, 0) BARSYNC;
    // ph2: quad(1,1) [A1 in regs]; stage HA1(tt+2)->buf0
    QRDB(0, 1)
    if (s2) QSTA1(tt + 2, 0)
    BARSYNC; LGKM0; QMM(1, 1) BARSYNC;
    // ph3: quad(0,1), re-read HA0; stage HB1(tt+2)->buf0; vmcnt
    QRDA(0, 0)
    if (s2) QSTB1(tt + 2, 0)
    BARSYNC; LGKM0; QMM(0, 1)
    if (s2) { VM(8); } else { VM(0); }
    BARSYNC;
    // ph4: buf1 quad(0,0); stage HA0(tt+2)->buf0
    QRDA(1, 0) QRDB(1, 0)
    if (s2) QSTA0(tt + 2, 0)
    BARSYNC; LGKM0; QMM(0, 0) BARSYNC;
    // ph5: quad(1,0); stage HB0(tt+3)->buf1
    QRDA(1, 1)
    if (s3) QSTB0(tt + 3, 1)
    BARSYNC; LGKM0; QMM(1, 0) BARSYNC;
    // ph6: quad(1,1); stage HA1(tt+3)->buf1
    QRDB(1, 1)
    if (s3) QSTA1(tt + 3, 1)
    BARSYNC; LGKM0; QMM(1, 1) BARSYNC;
    // ph7: quad(0,1), re-read HA0; stage HB1(tt+3)->buf1; vmcnt
    QRDA(1, 0)
    if (s3) QSTB1(tt + 3, 1)
    BARSYNC; LGKM0; QMM(0, 1)
    if (s3) { VM(8); }
    BARSYNC;
  }

  const int or0 = (lane >> 4) * 4;
#pragma unroll
  for (int mm = 0; mm < 4; ++mm)
#pragma unroll
    for (int j = 0; j < 6; ++j)
#pragma unroll
      for (int r = 0; r < 4; ++r) {
        int row = m0 + waveM * 64 + mm * 16 + or0 + r;
        int gc = n0 + waveN * 96 + j * 16 + lr0;
        int slab = gc >> 10;
        int col = gc & 1023;
        float x = acc[mm][j][r];
        if (slab == 0) {
          qh[(size_t)row * 1024 + col] = f2h(x + bq[col]);
        } else if (slab == 1) {
          kh[(size_t)row * 1024 + col] = f2h(x + bk[col]);
        } else {
          vS[(size_t)row * 1024 + col] = f2h(x + bv[col]);
        }
      }
}

// =====================================================================
// g8q: 8-phase 256x256 BK=64 1-term f16 NT GEMM (QK^T), m201 ledger.
// (R14-proven, unchanged.)
// =====================================================================
#define ST8(h, T, bufb)                                                   \
  do {                                                                    \
    const unsigned short* _s = ssrc[h] + (size_t)(T) * 64;                \
    char* _d = smem + (bufb) * 65536 + sdst[h];                           \
    GLOAD16(_s, _d);                                                      \
    GLOAD16(_s + 32, _d + 1024);                                          \
  } while (0)

#define RDA(bufb, qr)                                                     \
  _Pragma("unroll") for (int _i = 0; _i < 4; ++_i)                        \
  _Pragma("unroll") for (int _kk = 0; _kk < 2; ++_kk)                     \
      areg[_i][_kk] = *(const half8*)(smem + (bufb) * 65536 +             \
          ((waveM * 8 + (qr) * 4 + _i) * 2 + _kk) * 1024 + lane * 16);

#define RDB(bufb, qc)                                                     \
  _Pragma("unroll") for (int _j = 0; _j < 2; ++_j)                        \
  _Pragma("unroll") for (int _kk = 0; _kk < 2; ++_kk)                     \
      breg[_j][_kk] = *(const half8*)(smem + (bufb) * 65536 + 32768 +     \
          ((waveN * 4 + (qc) * 2 + _j) * 2 + _kk) * 1024 + lane * 16);

#define MM16(qr, qc)                                                      \
  __builtin_amdgcn_s_setprio(1);                                          \
  _Pragma("unroll") for (int _i = 0; _i < 4; ++_i)                        \
  _Pragma("unroll") for (int _j = 0; _j < 2; ++_j)                        \
  _Pragma("unroll") for (int _kk = 0; _kk < 2; ++_kk)                     \
      acc[(qr) * 4 + _i][(qc) * 2 + _j] =                                 \
          __builtin_amdgcn_mfma_f32_16x16x32_f16(                         \
              areg[_i][_kk], breg[_j][_kk],                               \
              acc[(qr) * 4 + _i][(qc) * 2 + _j], 0, 0, 0);                \
  __builtin_amdgcn_s_setprio(0);

__global__ __launch_bounds__(512, 2) void g8q_kernel(
    const unsigned short* __restrict__ Abase, size_t Astr, int lda,
    const unsigned short* __restrict__ Bbase, size_t Bstr, int ldb,
    float* __restrict__ outF, size_t Ostr, int ldo, int K) {
  __shared__ __align__(16) char smem[131072];
  const int t = threadIdx.x, wid = t >> 6, lane = t & 63;
  const int waveM = wid >> 2, waveN = wid & 3;
  const int lr0 = lane & 15, lk0 = (lane >> 4) * 8;
  const int m0 = blockIdx.y * 256, n0 = blockIdx.x * 256;
  const unsigned short* A = Abase + (size_t)blockIdx.z * Astr;
  const unsigned short* B = Bbase + (size_t)blockIdx.z * Bstr;
  float* out = outF + (size_t)blockIdx.z * Ostr;

  const int rgA0 = (wid & 3) + ((wid >> 2) << 3);
  const int rgA1 = rgA0 + 4;
  const int cgB0 = (wid & 1) + ((wid >> 1) << 2);
  const int cgB1 = cgB0 + 2;
  const unsigned short* ssrc[4];
  int sdst[4];
  ssrc[0] = A + (size_t)(m0 + rgA0 * 16 + lr0) * lda + lk0;
  ssrc[1] = A + (size_t)(m0 + rgA1 * 16 + lr0) * lda + lk0;
  ssrc[2] = B + (size_t)(n0 + cgB0 * 16 + lr0) * ldb + lk0;
  ssrc[3] = B + (size_t)(n0 + cgB1 * 16 + lr0) * ldb + lk0;
  sdst[0] = (rgA0 * 2) * 1024;
  sdst[1] = (rgA1 * 2) * 1024;
  sdst[2] = 32768 + (cgB0 * 2) * 1024;
  sdst[3] = 32768 + (cgB1 * 2) * 1024;

  const int NT = K >> 6, NT2 = NT >> 1;
  f32x4 acc[8][4] = {};
  half8 areg[4][2], breg[2][2];

  ST8(0, 0, 0); ST8(2, 0, 0); ST8(1, 0, 0); ST8(3, 0, 0);
  ST8(2, 1, 1); ST8(1, 1, 1); ST8(3, 1, 1);
  VM(6);
  BARSYNC;
  __builtin_amdgcn_sched_barrier(0);

#pragma unroll 1
  for (int it = 0; it < NT2; ++it) {
    const int tt = 2 * it;
    const bool s2 = (tt + 2) < NT;
    const bool s3 = (tt + 3) < NT;
    RDA(0, 0) RDB(0, 0)
    ST8(0, tt + 1, 1);
    BARSYNC; LGKM0; MM16(0, 0) BARSYNC;
    RDA(0, 1)
    if (s2) ST8(2, tt + 2, 0);
    BARSYNC; LGKM0; MM16(1, 0) BARSYNC;
    RDB(0, 1)
    if (s2) ST8(1, tt + 2, 0);
    BARSYNC; LGKM0; MM16(1, 1) BARSYNC;
    RDA(0, 0)
    if (s2) ST8(3, tt + 2, 0);
    BARSYNC; LGKM0; MM16(0, 1)
    if (s2) { VM(6); } else { VM(0); }
    BARSYNC;
    RDA(1, 0) RDB(1, 0)
    if (s2) ST8(0, tt + 2, 0);
    BARSYNC; LGKM0; MM16(0, 0) BARSYNC;
    RDA(1, 1)
    if (s3) ST8(2, tt + 3, 1);
    BARSYNC; LGKM0; MM16(1, 0) BARSYNC;
    RDB(1, 1)
    if (s3) ST8(1, tt + 3, 1);
    BARSYNC; LGKM0; MM16(1, 1) BARSYNC;
    RDA(1, 0)
    if (s3) ST8(3, tt + 3, 1);
    BARSYNC; LGKM0; MM16(0, 1)
    if (s3) { VM(6); }
    BARSYNC;
  }

  const int or0 = (lane >> 4) * 4;
#pragma unroll
  for (int mm = 0; mm < 8; ++mm)
#pragma unroll
    for (int cg = 0; cg < 4; ++cg)
#pragma unroll
      for (int r = 0; r < 4; ++r)
        out[(size_t)(m0 + waveM * 128 + mm * 16 + or0 + r) * ldo +
            (n0 + waveN * 64 + cg * 16 + lr0)] = acc[mm][cg][r];
}

// =====================================================================
// g1t: 1-term f16 NT GEMM (PV), 128x256 tile, BK=64, tri-144KB,
// 6 slots/wave, VM(6). (R18-proven, unchanged.)
// =====================================================================
__global__ __launch_bounds__(512, 2) void g1t_kernel(
    const unsigned short* __restrict__ Abase, size_t Astr, int lda,
    const unsigned short* __restrict__ Bbase, size_t Bstr, int ldb,
    float* __restrict__ outF, size_t Ostr, int ldo, int K) {
  __shared__ __align__(16) char smem[3 * 48 * 1024];
  const int t = threadIdx.x, wid = t >> 6, lane = t & 63;
  const int waveM = wid >> 2, waveN = wid & 3;
  const int lr0 = lane & 15, lk0 = (lane >> 4) * 8;
  const int m0 = blockIdx.y * 128, n0 = blockIdx.x * 256;
  const unsigned short* A = Abase + (size_t)blockIdx.z * Astr;
  const unsigned short* B = Bbase + (size_t)blockIdx.z * Bstr;
  float* out = outF + (size_t)blockIdx.z * Ostr;

  const unsigned short* slot_src[6];
#pragma unroll
  for (int s = 0; s < 6; ++s) {
    int si = 6 * wid + s;
    const unsigned short* p;
    if (si < 8)       p = A + (size_t)(m0 + si * 16 + lr0) * lda + lk0;
    else if (si < 16) p = A + (size_t)(m0 + (si - 8) * 16 + lr0) * lda + 32 + lk0;
    else if (si < 32) p = B + (size_t)(n0 + (si - 16) * 16 + lr0) * ldb + lk0;
    else              p = B + (size_t)(n0 + (si - 32) * 16 + lr0) * ldb + 32 + lk0;
    slot_src[s] = p;
  }

  const int NTILES = K >> 6;
  f32x4 acc[4][4] = {};

#pragma unroll
  for (int tt = 0; tt < 2; ++tt)
#pragma unroll
    for (int s = 0; s < 6; ++s)
      GLOAD16(slot_src[s] + (size_t)tt * 64,
              smem + tt * 49152 + (6 * wid + s) * 1024);
  VM(6);
  BARSYNC;
  __builtin_amdgcn_sched_barrier(0);

  for (int tile = 0; tile < NTILES; ++tile) {
    const int cur = tile % 3, nxt = (tile + 2) % 3;
    const bool do_stage = (tile + 2) < NTILES;
    const char* cb = smem + cur * 49152;
    char* nb = smem + nxt * 49152;
    half8 blo[4], bhi[4];
#pragma unroll
    for (int p = 0; p < 4; ++p) {
      const int mg = waveM * 4 + p;
      half8 alo = *(const half8*)(cb + mg * 1024 + lane * 16);
      half8 ahi = *(const half8*)(cb + (8 + mg) * 1024 + lane * 16);
      if (p == 0) {
#pragma unroll
        for (int j = 0; j < 4; ++j) {
          int ng = waveN * 4 + j;
          blo[j] = *(const half8*)(cb + (16 + ng) * 1024 + lane * 16);
          bhi[j] = *(const half8*)(cb + (32 + ng) * 1024 + lane * 16);
        }
      }
      if (do_stage && p < 3) {
#pragma unroll
        for (int s = 0; s < 2; ++s) {
          int slot = 2 * p + s;
          GLOAD16(slot_src[slot] + (size_t)(tile + 2) * 64,
                  nb + (6 * wid + slot) * 1024);
        }
      }
      __builtin_amdgcn_s_setprio(1);
#pragma unroll
      for (int j = 0; j < 4; ++j) {
        f32x4 c = acc[p][j];
        c = __builtin_amdgcn_mfma_f32_16x16x32_f16(alo, blo[j], c, 0, 0, 0);
        c = __builtin_amdgcn_mfma_f32_16x16x32_f16(ahi, bhi[j], c, 0, 0, 0);
        acc[p][j] = c;
      }
      __builtin_amdgcn_s_setprio(0);
    }
    if (tile + 1 < NTILES) {
      LGKM0;
      if (do_stage) VM(6); else VM(0);
      BARSYNC;
      __builtin_amdgcn_sched_barrier(0);
    }
  }

  const int or0 = (lane >> 4) * 4;
#pragma unroll
  for (int mm = 0; mm < 4; ++mm)
#pragma unroll
    for (int j = 0; j < 4; ++j)
#pragma unroll
      for (int r = 0; r < 4; ++r)
        out[(size_t)(m0 + waveM * 64 + mm * 16 + or0 + r) * ldo +
            (n0 + waveN * 64 + j * 16 + lr0)] = acc[mm][j][r];
}

// ---------- row softmax: fp32 [4096] -> f16 probs (in-place, pld stride) ----
__global__ __launch_bounds__(256) void softmax_rows_kernel(
    const float* Sm, unsigned short* P, int ncol, int pld) {
  const int t = threadIdx.x;
  const float* srow = Sm + (size_t)blockIdx.x * ncol;
  float4 v[4];
  float m = -3.4e38f;
#pragma unroll
  for (int i = 0; i < 4; ++i) {
    v[i] = ((const float4*)srow)[t + 256 * i];
    m = fmaxf(m, fmaxf(fmaxf(v[i].x, v[i].y), fmaxf(v[i].z, v[i].w)));
  }
#pragma unroll
  for (int off = 32; off >= 1; off >>= 1) m = fmaxf(m, __shfl_down(m, off));
  __shared__ float redm[4];
  if ((t & 63) == 0) redm[t >> 6] = m;
  __syncthreads();
  m = fmaxf(fmaxf(redm[0], redm[1]), fmaxf(redm[2], redm[3]));
  float s = 0.f;
#pragma unroll
  for (int i = 0; i < 4; ++i) {
    v[i].x = __expf(v[i].x - m);
    v[i].y = __expf(v[i].y - m);
    v[i].z = __expf(v[i].z - m);
    v[i].w = __expf(v[i].w - m);
    s += v[i].x + v[i].y + v[i].z + v[i].w;
  }
#pragma unroll
  for (int off = 32; off >= 1; off >>= 1) s += __shfl_down(s, off);
  __shared__ float reds[4];
  if ((t & 63) == 0) reds[t >> 6] = s;
  __syncthreads();
  s = reds[0] + reds[1] + reds[2] + reds[3];
  float inv = 1.f / s;
  unsigned short* prow = P + (size_t)blockIdx.x * pld;
#pragma unroll
  for (int i = 0; i < 4; ++i) {
    ushort4 o = make_ushort4(f2h(v[i].x * inv), f2h(v[i].y * inv),
                             f2h(v[i].z * inv), f2h(v[i].w * inv));
    ((ushort4*)prow)[t + 256 * i] = o;
  }
}

extern "C" void kernel_launch(void* const* d_in, const int* in_sizes, int n_in,
                              void* d_out, int out_size, void* d_ws, size_t ws_size,
                              hipStream_t stream) {
  const float* hs = (const float*)d_in[0];
  const float* Wq = (const float*)d_in[1];
  const float* bq = (const float*)d_in[2];
  const float* Wk = (const float*)d_in[3];
  const float* bk = (const float*)d_in[4];
  const float* Wv = (const float*)d_in[5];
  const float* bv = (const float*)d_in[6];
  float* out = (float*)d_out;

  constexpr int Ss = 4096, Hh = 1024;
  constexpr int Mm = 8192;
  constexpr size_t TOK = (size_t)Ss * Hh;
  char* ws = (char*)d_ws;
  const size_t MB = 1024 * 1024;

  unsigned short* qh = (unsigned short*)(ws + 0 * MB);
  unsigned short* kh = (unsigned short*)(ws + 16 * MB);
  unsigned short* vT = (unsigned short*)(ws + 32 * MB);  // [1024][8192]
  char* rb = ws + 48 * MB;
  unsigned short* hs_h = (unsigned short*)(rb + 0 * MB);
  unsigned short* hs_l = (unsigned short*)(rb + 16 * MB);
  unsigned short* WT = (unsigned short*)(rb + 32 * MB);   // [3072][1024]
  unsigned short* vS = (unsigned short*)(rb + 38 * MB);   // [8192][1024] staging
  float* Sf = (float*)rb;

  const bool big = ws_size >= (size_t)176 * MB;

  // 1) splits; W -> [3072][1024] f16 (q | k | v)
  split_pair_f16_kernel<<<dim3(Mm * Hh / 2048), 256, 0, stream>>>(hs, hs_h, hs_l);
  transpose_f16x3_kernel<<<dim3(32, 32, 3), 256, 0, stream>>>(Wq, Wk, Wv, WT);

  // 2) fused QKV projection (128x384 2-term, 8-phase ledger, VM(8))
  qkv8_kernel<<<dim3(8, 64), 512, 0, stream>>>(
      hs_h, hs_l, WT, bq, bk, bv, qh, kh, vS);

  // 2b) transpose V staging [8192][1024] -> vT [1024][8192]
  transpose_v_kernel<<<dim3(32, 256), 256, 0, stream>>>(vS, vT);

  if (big) {
    // 3) QK^T both batches (8-phase 256x256 BK=64) -> S fp32 slabs
    g8q_kernel<<<dim3(16, 16, 2), 512, 0, stream>>>(
        qh, TOK, Hh, kh, TOK, Hh, Sf, (size_t)Ss * Ss, Ss, Hh);
    // 4) softmax 8192 rows, fp32 -> f16 in-place strided (pld 8192)
    softmax_rows_kernel<<<dim3(2 * Ss), 256, 0, stream>>>(
        Sf, (unsigned short*)Sf, Ss, 2 * Ss);
    // 5) PV both batches (128x256 1-term, grid 256)
    g1t_kernel<<<dim3(4, 32, 2), 512, 0, stream>>>(
        (const unsigned short*)Sf, (size_t)Ss * 2 * Ss, 2 * Ss,
        vT, (size_t)Ss, Mm, out, TOK, Hh, Ss);
  } else {
    float* Sb = (float*)rb;
    unsigned short* Pb = (unsigned short*)(rb + 64 * MB);
    for (int b = 0; b < 2; ++b) {
      g8q_kernel<<<dim3(16, 16, 1), 512, 0, stream>>>(
          qh + b * TOK, 0, Hh, kh + b * TOK, 0, Hh, Sb, 0, Ss, Hh);
      softmax_rows_kernel<<<dim3(Ss), 256, 0, stream>>>(Sb, Pb, Ss, Ss);
      g1t_kernel<<<dim3(4, 32, 1), 512, 0, stream>>>(
          Pb, 0, Ss, vT + (size_t)b * Ss, 0, Mm, out + b * TOK, 0, Hh, Ss);
    }
  }
}